// Round 1
// baseline (2715.254 us; speedup 1.0000x reference)
//
#include <hip/hip_runtime.h>
#include <hip/hip_bf16.h>
#include <cstdint>

#define S_LEN   2048
#define DMODEL  2048
#define HHEADS  16
#define KVLORA  512
#define ROPE_D  64
#define QKD     576     // KVLORA + ROPE_D
#define QLORA   1536
#define TOPK    512
#define HQK     (HHEADS * QKD)     // 9216
#define HKV     (HHEADS * KVLORA)  // 8192

// ---------------------------------------------------------------------------
// NT GEMM: C[M,N] = A[M,K] * B[N,K]^T, all row-major fp32.
// ---------------------------------------------------------------------------
template<int BM, int BN, int BK, int TM, int TN>
__global__ __launch_bounds__(256)
void gemm_nt(const float* __restrict__ A, const float* __restrict__ B,
             float* __restrict__ C, int M, int N, int K) {
  __shared__ float As[BK][BM + 4];
  __shared__ float Bs[BK][BN + 4];
  const int tid = threadIdx.x;
  const int bm = blockIdx.y * BM;
  const int bn = blockIdx.x * BN;
  const int tx = tid % (BN / TN);
  const int ty = tid / (BN / TN);

  float acc[TM][TN];
#pragma unroll
  for (int i = 0; i < TM; ++i)
#pragma unroll
    for (int j = 0; j < TN; ++j) acc[i][j] = 0.f;

  constexpr int LA = (BM * BK) / (256 * 4);
  constexpr int LB = (BN * BK) / (256 * 4);

  for (int k0 = 0; k0 < K; k0 += BK) {
#pragma unroll
    for (int l = 0; l < LA; ++l) {
      int idx = (tid + l * 256) * 4;
      int r = idx / BK, c = idx % BK;
      float4 v = *(const float4*)(A + (size_t)(bm + r) * K + k0 + c);
      As[c + 0][r] = v.x; As[c + 1][r] = v.y; As[c + 2][r] = v.z; As[c + 3][r] = v.w;
    }
#pragma unroll
    for (int l = 0; l < LB; ++l) {
      int idx = (tid + l * 256) * 4;
      int r = idx / BK, c = idx % BK;
      float4 v = *(const float4*)(B + (size_t)(bn + r) * K + k0 + c);
      Bs[c + 0][r] = v.x; Bs[c + 1][r] = v.y; Bs[c + 2][r] = v.z; Bs[c + 3][r] = v.w;
    }
    __syncthreads();
#pragma unroll
    for (int k = 0; k < BK; ++k) {
      float a[TM], b[TN];
#pragma unroll
      for (int i = 0; i < TM; i += 4) {
        float4 v = *(const float4*)&As[k][ty * TM + i];
        a[i] = v.x; a[i + 1] = v.y; a[i + 2] = v.z; a[i + 3] = v.w;
      }
#pragma unroll
      for (int j = 0; j < TN; j += 4) {
        float4 v = *(const float4*)&Bs[k][tx * TN + j];
        b[j] = v.x; b[j + 1] = v.y; b[j + 2] = v.z; b[j + 3] = v.w;
      }
#pragma unroll
      for (int i = 0; i < TM; ++i)
#pragma unroll
        for (int j = 0; j < TN; ++j)
          acc[i][j] = fmaf(a[i], b[j], acc[i][j]);
    }
    __syncthreads();
  }

#pragma unroll
  for (int i = 0; i < TM; ++i) {
    float* crow = C + (size_t)(bm + ty * TM + i) * N + bn + tx * TN;
#pragma unroll
    for (int j = 0; j < TN; j += 4) {
      *(float4*)(crow + j) =
          make_float4(acc[i][j], acc[i][j + 1], acc[i][j + 2], acc[i][j + 3]);
    }
  }
}

// ---------------------------------------------------------------------------
// Row-wise RMSNorm in place: x[row] = w * x[row] * rsqrt(mean(x^2)+eps)
// ---------------------------------------------------------------------------
__global__ __launch_bounds__(256)
void rmsnorm_inplace(float* __restrict__ x, const float* __restrict__ w,
                     int n, float inv_n) {
  const int row = blockIdx.x;
  float* p = x + (size_t)row * n;
  const int tid = threadIdx.x;
  const int n4 = n / 4;
  float ss = 0.f;
  for (int i = tid; i < n4; i += 256) {
    float4 v = ((const float4*)p)[i];
    ss += v.x * v.x + v.y * v.y + v.z * v.z + v.w * v.w;
  }
#pragma unroll
  for (int d = 32; d >= 1; d >>= 1) ss += __shfl_xor(ss, d);
  __shared__ float wsum[4];
  if ((tid & 63) == 0) wsum[tid >> 6] = ss;
  __syncthreads();
  float tot = wsum[0] + wsum[1] + wsum[2] + wsum[3];
  float inv = rsqrtf(tot * inv_n + 1e-6f);
  for (int i = tid; i < n4; i += 256) {
    float4 v = ((const float4*)p)[i];
    float4 g = ((const float4*)w)[i];
    ((float4*)p)[i] = make_float4(g.x * v.x * inv, g.y * v.y * inv,
                                  g.z * v.z * inv, g.w * v.w * inv);
  }
}

// ---------------------------------------------------------------------------
// RoPE on q's pe slice, in place. Each thread owns a (r, r+32) pair -> no race.
// ---------------------------------------------------------------------------
__global__ __launch_bounds__(256)
void rope_q(float* __restrict__ q, const float* __restrict__ cs,
            const float* __restrict__ sn) {
  const int s = blockIdx.x;
  const int tid = threadIdx.x;
  __shared__ float c_s[64], s_s[64];
  if (tid < 64) { c_s[tid] = cs[s * 64 + tid]; s_s[tid] = sn[s * 64 + tid]; }
  __syncthreads();
  for (int i = tid; i < HHEADS * 32; i += 256) {
    int h = i >> 5, r = i & 31;
    size_t base = (size_t)s * HQK + h * QKD + KVLORA;
    float x1 = q[base + r], x2 = q[base + r + 32];
    q[base + r]      = x1 * c_s[r]      - x2 * s_s[r];
    q[base + r + 32] = x2 * c_s[r + 32] + x1 * s_s[r + 32];
  }
}

// ---------------------------------------------------------------------------
// kv row build: rmsnorm(ckv[:512]) * w_ln  ||  rope(ckv[512:576])
// One wave per row.
// ---------------------------------------------------------------------------
__global__ __launch_bounds__(64)
void kv_build(const float* __restrict__ ckv, const float* __restrict__ lnw,
              const float* __restrict__ cs, const float* __restrict__ sn,
              float* __restrict__ kv) {
  const int s = blockIdx.x;
  const int lane = threadIdx.x;
  const float* row = ckv + (size_t)s * QKD;
  float4 a = ((const float4*)row)[lane * 2];
  float4 b = ((const float4*)row)[lane * 2 + 1];
  float ss = a.x * a.x + a.y * a.y + a.z * a.z + a.w * a.w +
             b.x * b.x + b.y * b.y + b.z * b.z + b.w * b.w;
#pragma unroll
  for (int d = 32; d >= 1; d >>= 1) ss += __shfl_xor(ss, d);
  float inv = rsqrtf(ss * (1.f / KVLORA) + 1e-6f);
  float4 wa = ((const float4*)lnw)[lane * 2];
  float4 wb = ((const float4*)lnw)[lane * 2 + 1];
  float* orow = kv + (size_t)s * QKD;
  ((float4*)orow)[lane * 2] =
      make_float4(a.x * wa.x * inv, a.y * wa.y * inv, a.z * wa.z * inv, a.w * wa.w * inv);
  ((float4*)orow)[lane * 2 + 1] =
      make_float4(b.x * wb.x * inv, b.y * wb.y * inv, b.z * wb.z * inv, b.w * wb.w * inv);
  // rope (read from ckv, write to kv -> no in-place hazard)
  float x = row[KVLORA + lane];
  int partner = (lane < 32) ? lane + 32 : lane - 32;
  float other = row[KVLORA + partner];
  float rot = (lane < 32) ? -other : other;
  orow[KVLORA + lane] = x * cs[s * 64 + lane] + rot * sn[s * 64 + lane];
}

// ---------------------------------------------------------------------------
// Sparse masked attention. One block (256 thr) per query row s.
//  - dedupe topk via 2048-bit LDS bitmask (duplicates must count once)
//  - causal filter t <= s
//  - scores for all 16 heads share each kv-row read
//  - softmax unnormalized; divide by sum at epilogue
// ---------------------------------------------------------------------------
__global__ __launch_bounds__(256)
void attn_sparse(const float* __restrict__ q, const float* __restrict__ kv,
                 const int* __restrict__ topk, float* __restrict__ attn_out) {
  const int s = blockIdx.x;
  const int tid = threadIdx.x;
  const int lane = tid & 63;
  const int wv = tid >> 6;

  __shared__ unsigned int mask[64];
  __shared__ int list[TOPK];
  __shared__ int nk_s;
  __shared__ float qt[QKD][16];    // q^T, pre-scaled
  __shared__ float sc[TOPK][18];   // scores [key][head], row stride 18 (72B, float2-aligned)
  __shared__ float hrcp[16];

  if (tid < 64) mask[tid] = 0u;
  __syncthreads();
  for (int i = tid; i < TOPK; i += 256) {
    int t = topk[(size_t)s * TOPK + i];
    if (t <= s) atomicOr(&mask[t >> 5], 1u << (t & 31));
  }
  __syncthreads();

  if (wv == 0) {
    unsigned int w = mask[lane];
    int cnt = __popc(w);
    int incl = cnt;
#pragma unroll
    for (int d = 1; d < 64; d <<= 1) {
      int o = __shfl_up(incl, d);
      if (lane >= d) incl += o;
    }
    if (lane == 63) nk_s = incl;
    int pos = incl - cnt;
    while (w) {
      int b = __ffs(w) - 1;
      list[pos++] = (lane << 5) + b;
      w &= w - 1;
    }
  }

  const float scaling = 0.041666666666666664f;  // 576^-0.5
  for (int h = 0; h < 16; ++h)
    for (int d = tid; d < QKD; d += 256)
      qt[d][h] = q[(size_t)s * HQK + h * QKD + d] * scaling;
  __syncthreads();
  const int nk = nk_s;  // >= 1 (diagonal always allowed)

  // ---- scores: each thread owns key slots tid and tid+256 ----
  {
    const int k0 = tid, k1 = tid + 256;
    const bool a0 = k0 < nk, a1 = k1 < nk;
    if (a0 || a1) {
      const int t0 = list[a0 ? k0 : 0];
      const int t1 = list[a1 ? k1 : 0];
      const float* r0 = kv + (size_t)t0 * QKD;
      const float* r1 = kv + (size_t)t1 * QKD;
      float acc0[16], acc1[16];
#pragma unroll
      for (int h = 0; h < 16; ++h) { acc0[h] = 0.f; acc1[h] = 0.f; }
      for (int d = 0; d < QKD; d += 4) {
        float4 v0 = *(const float4*)(r0 + d);
        float4 v1 = *(const float4*)(r1 + d);
        float e0[4] = {v0.x, v0.y, v0.z, v0.w};
        float e1[4] = {v1.x, v1.y, v1.z, v1.w};
#pragma unroll
        for (int dd = 0; dd < 4; ++dd) {
          const float4* qr = (const float4*)qt[d + dd];  // broadcast (same addr all lanes)
          float4 q0 = qr[0], q1 = qr[1], q2 = qr[2], q3 = qr[3];
          float qv[16] = {q0.x, q0.y, q0.z, q0.w, q1.x, q1.y, q1.z, q1.w,
                          q2.x, q2.y, q2.z, q2.w, q3.x, q3.y, q3.z, q3.w};
#pragma unroll
          for (int h = 0; h < 16; ++h) {
            acc0[h] = fmaf(e0[dd], qv[h], acc0[h]);
            acc1[h] = fmaf(e1[dd], qv[h], acc1[h]);
          }
        }
      }
      if (a0) {
#pragma unroll
        for (int h = 0; h < 16; ++h) sc[k0][h] = acc0[h];
      }
      if (a1) {
#pragma unroll
        for (int h = 0; h < 16; ++h) sc[k1][h] = acc1[h];
      }
    }
  }
  __syncthreads();

  // ---- softmax per head (4 heads per wave) ----
  for (int h = wv; h < 16; h += 4) {
    float m = -1e30f;
    for (int k = lane; k < nk; k += 64) m = fmaxf(m, sc[k][h]);
#pragma unroll
    for (int d = 32; d >= 1; d >>= 1) m = fmaxf(m, __shfl_xor(m, d));
    float sum = 0.f;
    for (int k = lane; k < nk; k += 64) {
      float p = __expf(sc[k][h] - m);
      sc[k][h] = p;
      sum += p;
    }
#pragma unroll
    for (int d = 32; d >= 1; d >>= 1) sum += __shfl_xor(sum, d);
    if (lane == 0) hrcp[h] = 1.0f / sum;
  }
  __syncthreads();

  // ---- PV: thread owns dv pair (tid*2) across ALL 16 heads; v row read once/block ----
  float acc[16][2];
#pragma unroll
  for (int h = 0; h < 16; ++h) { acc[h][0] = 0.f; acc[h][1] = 0.f; }
  const int dv = tid * 2;
  for (int k = 0; k < nk; ++k) {
    int t = list[k];
    float2 v2 = *(const float2*)(kv + (size_t)t * QKD + dv);
    const float2* pr = (const float2*)sc[k];
    float po[16];
#pragma unroll
    for (int j = 0; j < 8; ++j) {
      float2 pp = pr[j];
      po[2 * j] = pp.x; po[2 * j + 1] = pp.y;
    }
#pragma unroll
    for (int h = 0; h < 16; ++h) {
      acc[h][0] = fmaf(po[h], v2.x, acc[h][0]);
      acc[h][1] = fmaf(po[h], v2.y, acc[h][1]);
    }
  }
#pragma unroll
  for (int h = 0; h < 16; ++h) {
    float r = hrcp[h];
    *(float2*)(attn_out + (size_t)s * HKV + h * KVLORA + dv) =
        make_float2(acc[h][0] * r, acc[h][1] * r);
  }
}

// ---------------------------------------------------------------------------
extern "C" void kernel_launch(void* const* d_in, const int* in_sizes, int n_in,
                              void* d_out, int out_size, void* d_ws, size_t ws_size,
                              hipStream_t stream) {
  const float* hidden   = (const float*)d_in[0];  // [1,2048,2048]
  const float* cosp     = (const float*)d_in[1];  // [1,2048,64]
  const float* sinp     = (const float*)d_in[2];
  const int*   topk     = (const int*)d_in[3];    // [1,2048,512]
  const float* w_q_a    = (const float*)d_in[4];  // [1536,2048]
  const float* w_q_a_ln = (const float*)d_in[5];  // [1536]
  const float* w_q_b    = (const float*)d_in[6];  // [9216,1536]
  const float* w_kv_a   = (const float*)d_in[7];  // [576,2048]
  const float* w_kv_ln  = (const float*)d_in[8];  // [512]
  const float* w_o      = (const float*)d_in[9];  // [2048,8192]
  float* out = (float*)d_out;

  float* ws   = (float*)d_ws;
  float* qa   = ws;                                  // 2048*1536
  float* qbuf = qa   + (size_t)S_LEN * QLORA;        // 2048*9216
  float* ckv  = qbuf + (size_t)S_LEN * HQK;          // 2048*576
  float* kv   = ckv  + (size_t)S_LEN * QKD;          // 2048*576
  float* attn = kv   + (size_t)S_LEN * QKD;          // 2048*8192

  // q_a = hidden @ w_q_a^T ; rmsnorm
  gemm_nt<128, 128, 16, 8, 8><<<dim3(QLORA / 128, S_LEN / 128), 256, 0, stream>>>(
      hidden, w_q_a, qa, S_LEN, QLORA, DMODEL);
  rmsnorm_inplace<<<S_LEN, 256, 0, stream>>>(qa, w_q_a_ln, QLORA, 1.f / QLORA);

  // q = q_resid @ w_q_b^T ; rope on pe slice
  gemm_nt<128, 128, 16, 8, 8><<<dim3(HQK / 128, S_LEN / 128), 256, 0, stream>>>(
      qa, w_q_b, qbuf, S_LEN, HQK, QLORA);
  rope_q<<<S_LEN, 256, 0, stream>>>(qbuf, cosp, sinp);

  // ckv = hidden @ w_kv_a^T ; kv row build
  gemm_nt<64, 64, 16, 4, 4><<<dim3(QKD / 64, S_LEN / 64), 256, 0, stream>>>(
      hidden, w_kv_a, ckv, S_LEN, QKD, DMODEL);
  kv_build<<<S_LEN, 64, 0, stream>>>(ckv, w_kv_ln, cosp, sinp, kv);

  // sparse attention
  attn_sparse<<<S_LEN, 256, 0, stream>>>(qbuf, kv, topk, attn);

  // out = attn @ w_o^T
  gemm_nt<128, 128, 16, 8, 8><<<dim3(DMODEL / 128, S_LEN / 128), 256, 0, stream>>>(
      attn, w_o, out, S_LEN, DMODEL, HKV);
}

// Round 2
// 1043.074 us; speedup vs baseline: 2.6031x; 2.6031x over previous
//
#include <hip/hip_runtime.h>
#include <hip/hip_bf16.h>
#include <cstdint>

#define S_LEN   2048
#define DMODEL  2048
#define HHEADS  16
#define KVLORA  512
#define ROPE_D  64
#define QKD     576     // KVLORA + ROPE_D
#define QLORA   1536
#define TOPK    512
#define HQK     (HHEADS * QKD)     // 9216
#define HKV     (HHEADS * KVLORA)  // 8192
#define NKV_PAD 640     // 576 padded to a multiple of 128

typedef __attribute__((ext_vector_type(4))) float f4v;
typedef __attribute__((ext_vector_type(8))) short short8;

__device__ __forceinline__ ushort f2bf(float f) {
  uint32_t u = __float_as_uint(f);
  uint32_t r = (u + 0x7fffu + ((u >> 16) & 1u)) >> 16;
  return (ushort)r;
}

__device__ __forceinline__ void gload_lds16(const ushort* g, ushort* l) {
  __builtin_amdgcn_global_load_lds(
      (const __attribute__((address_space(1))) unsigned int*)(uintptr_t)g,
      (__attribute__((address_space(3))) unsigned int*)(uintptr_t)l,
      16, 0, 0);
}

// ---------------------------------------------------------------------------
// bf16 NT GEMM (m97 structure): C[M,N] = A[M,K] * B[N,K]^T, fp32 out.
// 128x128 tile, BK=32, 4 waves, each wave 64x64 via 4x4 16x16x32 MFMA frags.
// ---------------------------------------------------------------------------
__global__ __launch_bounds__(256)
void gemm_bf16_nt(const ushort* __restrict__ A, const ushort* __restrict__ B,
                  float* __restrict__ C, int M, int N, int K) {
  __shared__ ushort As[128 * 32];
  __shared__ ushort Bs[128 * 32];
  const int tid = threadIdx.x;
  const int lane = tid & 63;
  const int w = tid >> 6;
  const int wr = w >> 1, wc = w & 1;
  const int bm = blockIdx.y * 128, bn = blockIdx.x * 128;

  f4v acc[4][4];
#pragma unroll
  for (int m = 0; m < 4; ++m)
#pragma unroll
    for (int n = 0; n < 4; ++n) acc[m][n] = (f4v){0.f, 0.f, 0.f, 0.f};

  const int ar0 = w * 32;            // this wave's 32 staging rows
  const int srow = lane >> 2;        // 0..15
  const int scol = (lane & 3) * 8;   // ushort offset within row (16B chunks)
  const int koff = (lane >> 4) * 8;  // fragment k-offset
  const int fr = lane & 15;          // fragment row/col

  for (int k0 = 0; k0 < K; k0 += 32) {
    __syncthreads();  // prev iteration's ds_reads done before overwrite
    gload_lds16(A + (size_t)(bm + ar0 + srow) * K + k0 + scol, &As[ar0 * 32]);
    gload_lds16(A + (size_t)(bm + ar0 + 16 + srow) * K + k0 + scol, &As[(ar0 + 16) * 32]);
    gload_lds16(B + (size_t)(bn + ar0 + srow) * K + k0 + scol, &Bs[ar0 * 32]);
    gload_lds16(B + (size_t)(bn + ar0 + 16 + srow) * K + k0 + scol, &Bs[(ar0 + 16) * 32]);
    __syncthreads();  // compiler drains vmcnt before s_barrier

    short8 a[4], b[4];
#pragma unroll
    for (int m = 0; m < 4; ++m)
      a[m] = *(const short8*)&As[(wr * 64 + m * 16 + fr) * 32 + koff];
#pragma unroll
    for (int n = 0; n < 4; ++n)
      b[n] = *(const short8*)&Bs[(wc * 64 + n * 16 + fr) * 32 + koff];
#pragma unroll
    for (int m = 0; m < 4; ++m)
#pragma unroll
      for (int n = 0; n < 4; ++n)
        acc[m][n] = __builtin_amdgcn_mfma_f32_16x16x32_bf16(a[m], b[n], acc[m][n], 0, 0, 0);
  }

  // C/D layout (m89-verified): col = lane&15, row = (lane>>4)*4 + reg
  const int crow0 = bm + wr * 64 + (lane >> 4) * 4;
  const int ccol0 = bn + wc * 64 + (lane & 15);
#pragma unroll
  for (int m = 0; m < 4; ++m)
#pragma unroll
    for (int n = 0; n < 4; ++n)
#pragma unroll
      for (int r = 0; r < 4; ++r)
        C[(size_t)(crow0 + m * 16 + r) * N + ccol0 + n * 16] = acc[m][n][r];
}

// ---------------------------------------------------------------------------
// fp32 -> bf16 casts
// ---------------------------------------------------------------------------
__global__ __launch_bounds__(256)
void cast_bf16(const float* __restrict__ in, ushort* __restrict__ out, int n8) {
  int i = blockIdx.x * 256 + threadIdx.x;
  if (i >= n8) return;
  float4 v0 = ((const float4*)in)[i * 2];
  float4 v1 = ((const float4*)in)[i * 2 + 1];
  short8 r;
  r[0] = f2bf(v0.x); r[1] = f2bf(v0.y); r[2] = f2bf(v0.z); r[3] = f2bf(v0.w);
  r[4] = f2bf(v1.x); r[5] = f2bf(v1.y); r[6] = f2bf(v1.z); r[7] = f2bf(v1.w);
  ((short8*)out)[i] = r;
}

// rows >= rows_in are written as zeros (pad for N%128 != 0)
__global__ __launch_bounds__(256)
void cast_pad_bf16(const float* __restrict__ in, ushort* __restrict__ out,
                   int rows_in, int cols, int n8) {
  int i = blockIdx.x * 256 + threadIdx.x;
  if (i >= n8) return;
  int row = (i * 8) / cols;
  short8 r = (short8){0, 0, 0, 0, 0, 0, 0, 0};
  if (row < rows_in) {
    float4 v0 = ((const float4*)in)[i * 2];
    float4 v1 = ((const float4*)in)[i * 2 + 1];
    r[0] = f2bf(v0.x); r[1] = f2bf(v0.y); r[2] = f2bf(v0.z); r[3] = f2bf(v0.w);
    r[4] = f2bf(v1.x); r[5] = f2bf(v1.y); r[6] = f2bf(v1.z); r[7] = f2bf(v1.w);
  }
  ((short8*)out)[i] = r;
}

// ---------------------------------------------------------------------------
// Row-wise RMSNorm, fp32 in -> bf16 out
// ---------------------------------------------------------------------------
__global__ __launch_bounds__(256)
void rmsnorm_bf16(const float* __restrict__ x, const float* __restrict__ w,
                  ushort* __restrict__ y, int n, float inv_n) {
  const int row = blockIdx.x;
  const float* p = x + (size_t)row * n;
  ushort* yp = y + (size_t)row * n;
  const int tid = threadIdx.x;
  const int n4 = n / 4;
  float ss = 0.f;
  for (int i = tid; i < n4; i += 256) {
    float4 v = ((const float4*)p)[i];
    ss += v.x * v.x + v.y * v.y + v.z * v.z + v.w * v.w;
  }
#pragma unroll
  for (int d = 32; d >= 1; d >>= 1) ss += __shfl_xor(ss, d);
  __shared__ float wsum[4];
  if ((tid & 63) == 0) wsum[tid >> 6] = ss;
  __syncthreads();
  float tot = wsum[0] + wsum[1] + wsum[2] + wsum[3];
  float inv = rsqrtf(tot * inv_n + 1e-6f);
  for (int i = tid; i < n4; i += 256) {
    float4 v = ((const float4*)p)[i];
    float4 g = ((const float4*)w)[i];
    ushort4 o;
    o.x = f2bf(g.x * v.x * inv); o.y = f2bf(g.y * v.y * inv);
    o.z = f2bf(g.z * v.z * inv); o.w = f2bf(g.w * v.w * inv);
    ((ushort4*)yp)[i] = o;
  }
}

// ---------------------------------------------------------------------------
// RoPE on q's pe slice, in place (fp32 q).
// ---------------------------------------------------------------------------
__global__ __launch_bounds__(256)
void rope_q(float* __restrict__ q, const float* __restrict__ cs,
            const float* __restrict__ sn) {
  const int s = blockIdx.x;
  const int tid = threadIdx.x;
  __shared__ float c_s[64], s_s[64];
  if (tid < 64) { c_s[tid] = cs[s * 64 + tid]; s_s[tid] = sn[s * 64 + tid]; }
  __syncthreads();
  for (int i = tid; i < HHEADS * 32; i += 256) {
    int h = i >> 5, r = i & 31;
    size_t base = (size_t)s * HQK + h * QKD + KVLORA;
    float x1 = q[base + r], x2 = q[base + r + 32];
    q[base + r]      = x1 * c_s[r]      - x2 * s_s[r];
    q[base + r + 32] = x2 * c_s[r + 32] + x1 * s_s[r + 32];
  }
}

// ---------------------------------------------------------------------------
// kv row build: rmsnorm(ckv[:512]) * w_ln  ||  rope(ckv[512:576])
// ckv has padded row stride NKV_PAD. One wave per row.
// ---------------------------------------------------------------------------
__global__ __launch_bounds__(64)
void kv_build(const float* __restrict__ ckv, const float* __restrict__ lnw,
              const float* __restrict__ cs, const float* __restrict__ sn,
              float* __restrict__ kv) {
  const int s = blockIdx.x;
  const int lane = threadIdx.x;
  const float* row = ckv + (size_t)s * NKV_PAD;
  float4 a = ((const float4*)row)[lane * 2];
  float4 b = ((const float4*)row)[lane * 2 + 1];
  float ss = a.x * a.x + a.y * a.y + a.z * a.z + a.w * a.w +
             b.x * b.x + b.y * b.y + b.z * b.z + b.w * b.w;
#pragma unroll
  for (int d = 32; d >= 1; d >>= 1) ss += __shfl_xor(ss, d);
  float inv = rsqrtf(ss * (1.f / KVLORA) + 1e-6f);
  float4 wa = ((const float4*)lnw)[lane * 2];
  float4 wb = ((const float4*)lnw)[lane * 2 + 1];
  float* orow = kv + (size_t)s * QKD;
  ((float4*)orow)[lane * 2] =
      make_float4(a.x * wa.x * inv, a.y * wa.y * inv, a.z * wa.z * inv, a.w * wa.w * inv);
  ((float4*)orow)[lane * 2 + 1] =
      make_float4(b.x * wb.x * inv, b.y * wb.y * inv, b.z * wb.z * inv, b.w * wb.w * inv);
  float x = row[KVLORA + lane];
  int partner = (lane < 32) ? lane + 32 : lane - 32;
  float other = row[KVLORA + partner];
  float rot = (lane < 32) ? -other : other;
  orow[KVLORA + lane] = x * cs[s * 64 + lane] + rot * sn[s * 64 + lane];
}

// ---------------------------------------------------------------------------
// Sparse masked attention (fp32 math), bf16 output for the w_o GEMM.
// ---------------------------------------------------------------------------
__global__ __launch_bounds__(256)
void attn_sparse(const float* __restrict__ q, const float* __restrict__ kv,
                 const int* __restrict__ topk, ushort* __restrict__ attn_out) {
  const int s = blockIdx.x;
  const int tid = threadIdx.x;
  const int lane = tid & 63;
  const int wv = tid >> 6;

  __shared__ unsigned int mask[64];
  __shared__ int list[TOPK];
  __shared__ int nk_s;
  __shared__ float qt[QKD][16];
  __shared__ float sc[TOPK][18];
  __shared__ float hrcp[16];

  if (tid < 64) mask[tid] = 0u;
  __syncthreads();
  for (int i = tid; i < TOPK; i += 256) {
    int t = topk[(size_t)s * TOPK + i];
    if (t <= s) atomicOr(&mask[t >> 5], 1u << (t & 31));
  }
  __syncthreads();

  if (wv == 0) {
    unsigned int w = mask[lane];
    int cnt = __popc(w);
    int incl = cnt;
#pragma unroll
    for (int d = 1; d < 64; d <<= 1) {
      int o = __shfl_up(incl, d);
      if (lane >= d) incl += o;
    }
    if (lane == 63) nk_s = incl;
    int pos = incl - cnt;
    while (w) {
      int b = __ffs(w) - 1;
      list[pos++] = (lane << 5) + b;
      w &= w - 1;
    }
  }

  const float scaling = 0.041666666666666664f;  // 576^-0.5
  for (int h = 0; h < 16; ++h)
    for (int d = tid; d < QKD; d += 256)
      qt[d][h] = q[(size_t)s * HQK + h * QKD + d] * scaling;
  __syncthreads();
  const int nk = nk_s;

  {
    const int k0 = tid, k1 = tid + 256;
    const bool a0 = k0 < nk, a1 = k1 < nk;
    if (a0 || a1) {
      const int t0 = list[a0 ? k0 : 0];
      const int t1 = list[a1 ? k1 : 0];
      const float* r0 = kv + (size_t)t0 * QKD;
      const float* r1 = kv + (size_t)t1 * QKD;
      float acc0[16], acc1[16];
#pragma unroll
      for (int h = 0; h < 16; ++h) { acc0[h] = 0.f; acc1[h] = 0.f; }
      for (int d = 0; d < QKD; d += 4) {
        float4 v0 = *(const float4*)(r0 + d);
        float4 v1 = *(const float4*)(r1 + d);
        float e0[4] = {v0.x, v0.y, v0.z, v0.w};
        float e1[4] = {v1.x, v1.y, v1.z, v1.w};
#pragma unroll
        for (int dd = 0; dd < 4; ++dd) {
          const float4* qr = (const float4*)qt[d + dd];
          float4 q0 = qr[0], q1 = qr[1], q2 = qr[2], q3 = qr[3];
          float qv[16] = {q0.x, q0.y, q0.z, q0.w, q1.x, q1.y, q1.z, q1.w,
                          q2.x, q2.y, q2.z, q2.w, q3.x, q3.y, q3.z, q3.w};
#pragma unroll
          for (int h = 0; h < 16; ++h) {
            acc0[h] = fmaf(e0[dd], qv[h], acc0[h]);
            acc1[h] = fmaf(e1[dd], qv[h], acc1[h]);
          }
        }
      }
      if (a0) {
#pragma unroll
        for (int h = 0; h < 16; ++h) sc[k0][h] = acc0[h];
      }
      if (a1) {
#pragma unroll
        for (int h = 0; h < 16; ++h) sc[k1][h] = acc1[h];
      }
    }
  }
  __syncthreads();

  for (int h = wv; h < 16; h += 4) {
    float m = -1e30f;
    for (int k = lane; k < nk; k += 64) m = fmaxf(m, sc[k][h]);
#pragma unroll
    for (int d = 32; d >= 1; d >>= 1) m = fmaxf(m, __shfl_xor(m, d));
    float sum = 0.f;
    for (int k = lane; k < nk; k += 64) {
      float p = __expf(sc[k][h] - m);
      sc[k][h] = p;
      sum += p;
    }
#pragma unroll
    for (int d = 32; d >= 1; d >>= 1) sum += __shfl_xor(sum, d);
    if (lane == 0) hrcp[h] = 1.0f / sum;
  }
  __syncthreads();

  float acc[16][2];
#pragma unroll
  for (int h = 0; h < 16; ++h) { acc[h][0] = 0.f; acc[h][1] = 0.f; }
  const int dv = tid * 2;
  for (int k = 0; k < nk; ++k) {
    int t = list[k];
    float2 v2 = *(const float2*)(kv + (size_t)t * QKD + dv);
    const float2* pr = (const float2*)sc[k];
    float po[16];
#pragma unroll
    for (int j = 0; j < 8; ++j) {
      float2 pp = pr[j];
      po[2 * j] = pp.x; po[2 * j + 1] = pp.y;
    }
#pragma unroll
    for (int h = 0; h < 16; ++h) {
      acc[h][0] = fmaf(po[h], v2.x, acc[h][0]);
      acc[h][1] = fmaf(po[h], v2.y, acc[h][1]);
    }
  }
#pragma unroll
  for (int h = 0; h < 16; ++h) {
    float r = hrcp[h];
    ushort2 o;
    o.x = f2bf(acc[h][0] * r);
    o.y = f2bf(acc[h][1] * r);
    *(ushort2*)(attn_out + (size_t)s * HKV + h * KVLORA + dv) = o;
  }
}

// ---------------------------------------------------------------------------
extern "C" void kernel_launch(void* const* d_in, const int* in_sizes, int n_in,
                              void* d_out, int out_size, void* d_ws, size_t ws_size,
                              hipStream_t stream) {
  const float* hidden   = (const float*)d_in[0];
  const float* cosp     = (const float*)d_in[1];
  const float* sinp     = (const float*)d_in[2];
  const int*   topk     = (const int*)d_in[3];
  const float* w_q_a    = (const float*)d_in[4];
  const float* w_q_a_ln = (const float*)d_in[5];
  const float* w_q_b    = (const float*)d_in[6];
  const float* w_kv_a   = (const float*)d_in[7];
  const float* w_kv_ln  = (const float*)d_in[8];
  const float* w_o      = (const float*)d_in[9];
  float* out = (float*)d_out;

  char* base = (char*)d_ws;
  // region0 (32MB): hid_bf | wqa_bf | qa | qa_bf — all dead before attention,
  // reused as attn_bf (exactly 32MB).
  ushort* hid_bf  = (ushort*)(base + 0);                       //  8,388,608
  ushort* wqa_bf  = (ushort*)(base + 8388608);                 //  6,291,456
  float*  qa      = (float*) (base + 14680064);                // 12,582,912
  ushort* qa_bf   = (ushort*)(base + 27262976);                //  6,291,456
  ushort* attn_bf = (ushort*)(base + 0);                       // 33,554,432 (alias)
  ushort* wqb_bf  = (ushort*)(base + 33554432);                // 28,311,552
  ushort* wkv_bf  = (ushort*)(base + 61865984);                //  2,621,440
  ushort* wo_bf   = (ushort*)(base + 64487424);                // 33,554,432
  float*  qbuf    = (float*) (base + 98041856);                // 75,497,472
  float*  ckv     = (float*) (base + 173539328);               //  5,242,880
  float*  kv      = (float*) (base + 178782208);               //  4,718,592

  // --- casts to bf16 ---
  cast_bf16<<<(S_LEN * DMODEL / 8 + 255) / 256, 256, 0, stream>>>(hidden, hid_bf, S_LEN * DMODEL / 8);
  cast_bf16<<<(QLORA * DMODEL / 8 + 255) / 256, 256, 0, stream>>>(w_q_a, wqa_bf, QLORA * DMODEL / 8);
  cast_bf16<<<(HQK * QLORA / 8 + 255) / 256, 256, 0, stream>>>(w_q_b, wqb_bf, HQK * QLORA / 8);
  cast_pad_bf16<<<(NKV_PAD * DMODEL / 8 + 255) / 256, 256, 0, stream>>>(w_kv_a, wkv_bf, QKD, DMODEL, NKV_PAD * DMODEL / 8);
  cast_bf16<<<(DMODEL * HKV / 8 + 255) / 256, 256, 0, stream>>>(w_o, wo_bf, DMODEL * HKV / 8);

  // --- q_a = hidden @ w_q_a^T ; rmsnorm -> bf16 ---
  gemm_bf16_nt<<<dim3(QLORA / 128, S_LEN / 128), 256, 0, stream>>>(
      hid_bf, wqa_bf, qa, S_LEN, QLORA, DMODEL);
  rmsnorm_bf16<<<S_LEN, 256, 0, stream>>>(qa, w_q_a_ln, qa_bf, QLORA, 1.f / QLORA);

  // --- q = q_resid @ w_q_b^T ; rope ---
  gemm_bf16_nt<<<dim3(HQK / 128, S_LEN / 128), 256, 0, stream>>>(
      qa_bf, wqb_bf, qbuf, S_LEN, HQK, QLORA);
  rope_q<<<S_LEN, 256, 0, stream>>>(qbuf, cosp, sinp);

  // --- ckv = hidden @ w_kv_a^T (padded N) ; kv build ---
  gemm_bf16_nt<<<dim3(NKV_PAD / 128, S_LEN / 128), 256, 0, stream>>>(
      hid_bf, wkv_bf, ckv, S_LEN, NKV_PAD, DMODEL);
  kv_build<<<S_LEN, 64, 0, stream>>>(ckv, w_kv_ln, cosp, sinp, kv);

  // --- sparse attention (fp32 math, bf16 out) ---
  attn_sparse<<<S_LEN, 256, 0, stream>>>(qbuf, kv, topk, attn_bf);

  // --- out = attn @ w_o^T ---
  gemm_bf16_nt<<<dim3(DMODEL / 128, S_LEN / 128), 256, 0, stream>>>(
      attn_bf, wo_bf, out, S_LEN, DMODEL, HKV);
}

// Round 5
// 755.850 us; speedup vs baseline: 3.5923x; 1.3800x over previous
//
#include <hip/hip_runtime.h>
#include <hip/hip_bf16.h>
#include <cstdint>

#define S_LEN   2048
#define DMODEL  2048
#define HHEADS  16
#define KVLORA  512
#define ROPE_D  64
#define QKD     576     // KVLORA + ROPE_D
#define QLORA   1536
#define TOPK    512
#define HQK     (HHEADS * QKD)     // 9216
#define HKV     (HHEADS * KVLORA)  // 8192
#define NKV_PAD 640     // 576 padded to a multiple of 128

typedef __attribute__((ext_vector_type(4))) float f4v;
typedef __attribute__((ext_vector_type(8))) short short8;
typedef __attribute__((ext_vector_type(2))) unsigned int u32x2;
typedef __attribute__((ext_vector_type(4))) unsigned int u32x4;

__device__ __forceinline__ ushort f2bf(float f) {
  uint32_t u = __float_as_uint(f);
  uint32_t r = (u + 0x7fffu + ((u >> 16) & 1u)) >> 16;
  return (ushort)r;
}
__device__ __forceinline__ float bf2f(ushort u) {
  return __uint_as_float(((uint32_t)u) << 16);
}

__device__ __forceinline__ void gload_lds16(const ushort* g, ushort* l) {
  __builtin_amdgcn_global_load_lds(
      (const __attribute__((address_space(1))) unsigned int*)(uintptr_t)g,
      (__attribute__((address_space(3))) unsigned int*)(uintptr_t)l,
      16, 0, 0);
}

// ---------------------------------------------------------------------------
// bf16 NT GEMM (m97 structure): C = A[M,K] * B[N,K]^T. fp32-out variant.
// ---------------------------------------------------------------------------
__global__ __launch_bounds__(256)
void gemm_bf16_nt(const ushort* __restrict__ A, const ushort* __restrict__ B,
                  float* __restrict__ C, int M, int N, int K) {
  __shared__ ushort As[128 * 32];
  __shared__ ushort Bs[128 * 32];
  const int tid = threadIdx.x;
  const int lane = tid & 63;
  const int w = tid >> 6;
  const int wr = w >> 1, wc = w & 1;
  const int bm = blockIdx.y * 128, bn = blockIdx.x * 128;

  f4v acc[4][4];
#pragma unroll
  for (int m = 0; m < 4; ++m)
#pragma unroll
    for (int n = 0; n < 4; ++n) acc[m][n] = (f4v){0.f, 0.f, 0.f, 0.f};

  const int ar0 = w * 32;
  const int srow = lane >> 2;
  const int scol = (lane & 3) * 8;
  const int koff = (lane >> 4) * 8;
  const int fr = lane & 15;

  for (int k0 = 0; k0 < K; k0 += 32) {
    __syncthreads();
    gload_lds16(A + (size_t)(bm + ar0 + srow) * K + k0 + scol, &As[ar0 * 32]);
    gload_lds16(A + (size_t)(bm + ar0 + 16 + srow) * K + k0 + scol, &As[(ar0 + 16) * 32]);
    gload_lds16(B + (size_t)(bn + ar0 + srow) * K + k0 + scol, &Bs[ar0 * 32]);
    gload_lds16(B + (size_t)(bn + ar0 + 16 + srow) * K + k0 + scol, &Bs[(ar0 + 16) * 32]);
    __syncthreads();

    short8 a[4], b[4];
#pragma unroll
    for (int m = 0; m < 4; ++m)
      a[m] = *(const short8*)&As[(wr * 64 + m * 16 + fr) * 32 + koff];
#pragma unroll
    for (int n = 0; n < 4; ++n)
      b[n] = *(const short8*)&Bs[(wc * 64 + n * 16 + fr) * 32 + koff];
#pragma unroll
    for (int m = 0; m < 4; ++m)
#pragma unroll
      for (int n = 0; n < 4; ++n)
        acc[m][n] = __builtin_amdgcn_mfma_f32_16x16x32_bf16(a[m], b[n], acc[m][n], 0, 0, 0);
  }

  const int crow0 = bm + wr * 64 + (lane >> 4) * 4;
  const int ccol0 = bn + wc * 64 + (lane & 15);
#pragma unroll
  for (int m = 0; m < 4; ++m)
#pragma unroll
    for (int n = 0; n < 4; ++n)
#pragma unroll
      for (int r = 0; r < 4; ++r)
        C[(size_t)(crow0 + m * 16 + r) * N + ccol0 + n * 16] = acc[m][n][r];
}

// bf16-out variant (for q_b output)
__global__ __launch_bounds__(256)
void gemm_bf16_nt_bf16out(const ushort* __restrict__ A, const ushort* __restrict__ B,
                          ushort* __restrict__ C, int M, int N, int K) {
  __shared__ ushort As[128 * 32];
  __shared__ ushort Bs[128 * 32];
  const int tid = threadIdx.x;
  const int lane = tid & 63;
  const int w = tid >> 6;
  const int wr = w >> 1, wc = w & 1;
  const int bm = blockIdx.y * 128, bn = blockIdx.x * 128;

  f4v acc[4][4];
#pragma unroll
  for (int m = 0; m < 4; ++m)
#pragma unroll
    for (int n = 0; n < 4; ++n) acc[m][n] = (f4v){0.f, 0.f, 0.f, 0.f};

  const int ar0 = w * 32;
  const int srow = lane >> 2;
  const int scol = (lane & 3) * 8;
  const int koff = (lane >> 4) * 8;
  const int fr = lane & 15;

  for (int k0 = 0; k0 < K; k0 += 32) {
    __syncthreads();
    gload_lds16(A + (size_t)(bm + ar0 + srow) * K + k0 + scol, &As[ar0 * 32]);
    gload_lds16(A + (size_t)(bm + ar0 + 16 + srow) * K + k0 + scol, &As[(ar0 + 16) * 32]);
    gload_lds16(B + (size_t)(bn + ar0 + srow) * K + k0 + scol, &Bs[ar0 * 32]);
    gload_lds16(B + (size_t)(bn + ar0 + 16 + srow) * K + k0 + scol, &Bs[(ar0 + 16) * 32]);
    __syncthreads();

    short8 a[4], b[4];
#pragma unroll
    for (int m = 0; m < 4; ++m)
      a[m] = *(const short8*)&As[(wr * 64 + m * 16 + fr) * 32 + koff];
#pragma unroll
    for (int n = 0; n < 4; ++n)
      b[n] = *(const short8*)&Bs[(wc * 64 + n * 16 + fr) * 32 + koff];
#pragma unroll
    for (int m = 0; m < 4; ++m)
#pragma unroll
      for (int n = 0; n < 4; ++n)
        acc[m][n] = __builtin_amdgcn_mfma_f32_16x16x32_bf16(a[m], b[n], acc[m][n], 0, 0, 0);
  }

  const int crow0 = bm + wr * 64 + (lane >> 4) * 4;
  const int ccol0 = bn + wc * 64 + (lane & 15);
#pragma unroll
  for (int m = 0; m < 4; ++m)
#pragma unroll
    for (int n = 0; n < 4; ++n)
#pragma unroll
      for (int r = 0; r < 4; ++r)
        C[(size_t)(crow0 + m * 16 + r) * N + ccol0 + n * 16] = f2bf(acc[m][n][r]);
}

// ---------------------------------------------------------------------------
// fp32 -> bf16 casts
// ---------------------------------------------------------------------------
__global__ __launch_bounds__(256)
void cast_bf16(const float* __restrict__ in, ushort* __restrict__ out, int n8) {
  int i = blockIdx.x * 256 + threadIdx.x;
  if (i >= n8) return;
  float4 v0 = ((const float4*)in)[i * 2];
  float4 v1 = ((const float4*)in)[i * 2 + 1];
  short8 r;
  r[0] = f2bf(v0.x); r[1] = f2bf(v0.y); r[2] = f2bf(v0.z); r[3] = f2bf(v0.w);
  r[4] = f2bf(v1.x); r[5] = f2bf(v1.y); r[6] = f2bf(v1.z); r[7] = f2bf(v1.w);
  ((short8*)out)[i] = r;
}

__global__ __launch_bounds__(256)
void cast_pad_bf16(const float* __restrict__ in, ushort* __restrict__ out,
                   int rows_in, int cols, int n8) {
  int i = blockIdx.x * 256 + threadIdx.x;
  if (i >= n8) return;
  int row = (i * 8) / cols;
  short8 r = (short8){0, 0, 0, 0, 0, 0, 0, 0};
  if (row < rows_in) {
    float4 v0 = ((const float4*)in)[i * 2];
    float4 v1 = ((const float4*)in)[i * 2 + 1];
    r[0] = f2bf(v0.x); r[1] = f2bf(v0.y); r[2] = f2bf(v0.z); r[3] = f2bf(v0.w);
    r[4] = f2bf(v1.x); r[5] = f2bf(v1.y); r[6] = f2bf(v1.z); r[7] = f2bf(v1.w);
  }
  ((short8*)out)[i] = r;
}

// ---------------------------------------------------------------------------
// RMSNorm fp32 -> bf16
// ---------------------------------------------------------------------------
__global__ __launch_bounds__(256)
void rmsnorm_bf16(const float* __restrict__ x, const float* __restrict__ w,
                  ushort* __restrict__ y, int n, float inv_n) {
  const int row = blockIdx.x;
  const float* p = x + (size_t)row * n;
  ushort* yp = y + (size_t)row * n;
  const int tid = threadIdx.x;
  const int n4 = n / 4;
  float ss = 0.f;
  for (int i = tid; i < n4; i += 256) {
    float4 v = ((const float4*)p)[i];
    ss += v.x * v.x + v.y * v.y + v.z * v.z + v.w * v.w;
  }
#pragma unroll
  for (int d = 32; d >= 1; d >>= 1) ss += __shfl_xor(ss, d);
  __shared__ float wsum[4];
  if ((tid & 63) == 0) wsum[tid >> 6] = ss;
  __syncthreads();
  float tot = wsum[0] + wsum[1] + wsum[2] + wsum[3];
  float inv = rsqrtf(tot * inv_n + 1e-6f);
  for (int i = tid; i < n4; i += 256) {
    float4 v = ((const float4*)p)[i];
    float4 g = ((const float4*)w)[i];
    ushort4 o;
    o.x = f2bf(g.x * v.x * inv); o.y = f2bf(g.y * v.y * inv);
    o.z = f2bf(g.z * v.z * inv); o.w = f2bf(g.w * v.w * inv);
    ((ushort4*)yp)[i] = o;
  }
}

// ---------------------------------------------------------------------------
// RoPE + scale (576^-0.5) in place on bf16 q [S][16][576]
// ---------------------------------------------------------------------------
__global__ __launch_bounds__(256)
void rope_scale(ushort* __restrict__ q, const float* __restrict__ cs,
                const float* __restrict__ sn) {
  const int s = blockIdx.x;
  const int tid = threadIdx.x;
  __shared__ float c_s[64], s_s[64];
  if (tid < 64) { c_s[tid] = cs[s * 64 + tid]; s_s[tid] = sn[s * 64 + tid]; }
  __syncthreads();
  const float SC = 0.041666666666666664f;  // 576^-0.5
  ushort* qrow = q + (size_t)s * HQK;
  // nope dims (0..511) scale in place: 16 heads x 64 chunks of 8
  for (int i = tid; i < 1024; i += 256) {
    int hh = i >> 6, c = i & 63;
    ushort* p = qrow + hh * QKD + c * 8;
    short8 v = *(short8*)p;
#pragma unroll
    for (int e = 0; e < 8; ++e) v[e] = (short)f2bf(bf2f((ushort)v[e]) * SC);
    *(short8*)p = v;
  }
  // pe dims: rope pair (r, r+32) owned by one thread
  for (int i = tid; i < HHEADS * 32; i += 256) {
    int hh = i >> 5, r = i & 31;
    ushort* bp = qrow + hh * QKD + KVLORA;
    float x1 = bf2f(bp[r]), x2 = bf2f(bp[r + 32]);
    bp[r]      = f2bf((x1 * c_s[r] - x2 * s_s[r]) * SC);
    bp[r + 32] = f2bf((x2 * c_s[r + 32] + x1 * s_s[r + 32]) * SC);
  }
}

// ---------------------------------------------------------------------------
// kv row build -> bf16: rmsnorm(ckv[:512])*w_ln || rope(ckv[512:576])
// ---------------------------------------------------------------------------
__global__ __launch_bounds__(64)
void kv_build_bf(const float* __restrict__ ckv, const float* __restrict__ lnw,
                 const float* __restrict__ cs, const float* __restrict__ sn,
                 ushort* __restrict__ kvbf) {
  const int s = blockIdx.x;
  const int lane = threadIdx.x;
  const float* row = ckv + (size_t)s * NKV_PAD;
  float4 a = ((const float4*)row)[lane * 2];
  float4 b = ((const float4*)row)[lane * 2 + 1];
  float ss = a.x * a.x + a.y * a.y + a.z * a.z + a.w * a.w +
             b.x * b.x + b.y * b.y + b.z * b.z + b.w * b.w;
#pragma unroll
  for (int d = 32; d >= 1; d >>= 1) ss += __shfl_xor(ss, d);
  float inv = rsqrtf(ss * (1.f / KVLORA) + 1e-6f);
  float4 wa = ((const float4*)lnw)[lane * 2];
  float4 wb = ((const float4*)lnw)[lane * 2 + 1];
  ushort* orow = kvbf + (size_t)s * QKD;
  short8 o;
  o[0] = f2bf(a.x * wa.x * inv); o[1] = f2bf(a.y * wa.y * inv);
  o[2] = f2bf(a.z * wa.z * inv); o[3] = f2bf(a.w * wa.w * inv);
  o[4] = f2bf(b.x * wb.x * inv); o[5] = f2bf(b.y * wb.y * inv);
  o[6] = f2bf(b.z * wb.z * inv); o[7] = f2bf(b.w * wb.w * inv);
  *(short8*)(orow + lane * 8) = o;
  float x = row[KVLORA + lane];
  int partner = (lane < 32) ? lane + 32 : lane - 32;
  float other = row[KVLORA + partner];
  float rot = (lane < 32) ? -other : other;
  orow[KVLORA + lane] = f2bf(x * cs[s * 64 + lane] + rot * sn[s * 64 + lane]);
}

// ---------------------------------------------------------------------------
// MFMA sparse attention. One block per query row.
// Swapped QK^T: S^T[key,head] = mfma(K_frag, q_frag). S in registers,
// softmax via shfl_xor + LDS cross-wave partials. P -> LDS (A-frag layout).
// PV: V staged subtiled in LDS as VT[dg][key][slot] (slot = dim within 16),
// consumed via ds_read_b64_tr_b16 using the m156-verified address pattern:
//   addr(lane) = window_base(group) + (lane&15)*8 bytes
// => lane l, elem j receives window[(l&15) + 16*j] (column l&15 of the 4x16
// collected matrix). window_base = dg*1024 + g*256 bytes -> lane (g,h) gets
// VT[dg][key g*8+j][slot h]; offset:128 walks to keys g*8+4..7.
// ---------------------------------------------------------------------------
__global__ __launch_bounds__(256)
void attn_mfma(const ushort* __restrict__ qbf, const ushort* __restrict__ kvbf,
               const int* __restrict__ topk, ushort* __restrict__ attn_out) {
  const int s = blockIdx.x;
  const int tid = threadIdx.x;
  const int lane = tid & 63;
  const int w = tid >> 6;
  const int g = lane >> 4;   // 0..3
  const int h = lane & 15;   // fragment row (key for A / head for B/D-col)

  __shared__ unsigned int msk[64];
  __shared__ int list[544];
  __shared__ int nk_s;
  __shared__ float wred[4][16];
  __shared__ float denom_lds[16];
  __shared__ ushort P_lds[16][520];     // [head][key] bf16, unnormalized probs
  __shared__ ushort VT[32 * 32 * 16];   // [dimgroup][key][16] per 32-key chunk

  if (tid < 64) msk[tid] = 0u;
  {  // zero P_lds (pad keys must contribute 0 to PV)
    uint* pz = (uint*)&P_lds[0][0];
    for (int i = tid; i < 16 * 260; i += 256) pz[i] = 0u;
  }
  __syncthreads();
  for (int i = tid; i < TOPK; i += 256) {
    int t = topk[(size_t)s * TOPK + i];
    if (t <= s) atomicOr(&msk[t >> 5], 1u << (t & 31));
  }
  __syncthreads();

  if (w == 0) {
    unsigned int b = msk[lane];
    int cnt = __popc(b);
    int incl = cnt;
#pragma unroll
    for (int d = 1; d < 64; d <<= 1) {
      int o = __shfl_up(incl, d);
      if (lane >= d) incl += o;
    }
    if (lane == 63) nk_s = incl;
    int pos = incl - cnt;
    while (b) {
      int bit = __ffs(b) - 1;
      list[pos++] = (lane << 5) + bit;
      b &= b - 1;
    }
    int nkv = __shfl(incl, 63);
    for (int i = nkv + lane; i < 544; i += 64) list[i] = s;  // pad with own row
  }

  // q B-frags: head h, all 18 k-steps (q pre-scaled by 576^-0.5)
  short8 qf[18];
  const ushort* qrow = qbf + (size_t)s * HQK + h * QKD;
#pragma unroll
  for (int kk = 0; kk < 18; ++kk)
    qf[kk] = *(const short8*)(qrow + kk * 32 + g * 8);

  __syncthreads();
  const int nk = nk_s;
  const int nt16 = (nk + 15) >> 4;
  const int nkc = (nk + 31) >> 5;

  // ---- scores: wave w owns m-tiles {w, w+4, w+8, ...}; pairs for ILP ----
  float sreg[8][4];
#pragma unroll
  for (int t2 = 0; t2 < 4; ++t2) {
    const int mtA = w + 8 * t2;
    const int mtB = mtA + 4;
    if (mtA >= nt16) break;
    const bool hasB = (mtB < nt16);
    const ushort* rA = kvbf + (size_t)list[mtA * 16 + h] * QKD;
    const ushort* rB = kvbf + (size_t)list[(hasB ? mtB : mtA) * 16 + h] * QKD;
    f4v aA = (f4v){0.f, 0.f, 0.f, 0.f};
    f4v aB = (f4v){0.f, 0.f, 0.f, 0.f};
#pragma unroll 6
    for (int kk = 0; kk < 18; ++kk) {
      short8 kfA = *(const short8*)(rA + kk * 32 + g * 8);
      short8 kfB = *(const short8*)(rB + kk * 32 + g * 8);
      aA = __builtin_amdgcn_mfma_f32_16x16x32_bf16(kfA, qf[kk], aA, 0, 0, 0);
      aB = __builtin_amdgcn_mfma_f32_16x16x32_bf16(kfB, qf[kk], aB, 0, 0, 0);
    }
#pragma unroll
    for (int r = 0; r < 4; ++r) {
      sreg[2 * t2][r] = aA[r];
      sreg[2 * t2 + 1][r] = aB[r];
    }
  }

  // ---- softmax (lane holds keys 16*(w+4*ti)+4g+r for head h) ----
  float mloc = -3e38f;
#pragma unroll
  for (int ti = 0; ti < 8; ++ti) {
    int keyb = 16 * (w + 4 * ti) + 4 * g;
#pragma unroll
    for (int r = 0; r < 4; ++r) {
      if (keyb + r >= nk) sreg[ti][r] = -3e38f;
      mloc = fmaxf(mloc, sreg[ti][r]);
    }
  }
  mloc = fmaxf(mloc, __shfl_xor(mloc, 16));
  mloc = fmaxf(mloc, __shfl_xor(mloc, 32));
  if (g == 0) wred[w][h] = mloc;
  __syncthreads();
  float mg = fmaxf(fmaxf(wred[0][h], wred[1][h]), fmaxf(wred[2][h], wred[3][h]));
  float psum = 0.f;
#pragma unroll
  for (int ti = 0; ti < 8; ++ti)
#pragma unroll
    for (int r = 0; r < 4; ++r) {
      float p = __expf(sreg[ti][r] - mg);
      sreg[ti][r] = p;
      psum += p;
    }
  psum += __shfl_xor(psum, 16);
  psum += __shfl_xor(psum, 32);
  __syncthreads();  // everyone done reading wred (max) before overwrite
  if (g == 0) wred[w][h] = psum;
  __syncthreads();
  float tot = wred[0][h] + wred[1][h] + wred[2][h] + wred[3][h];
  if (w == 0 && g == 0) denom_lds[h] = 1.0f / tot;

  // write P (bf16, unnormalized) to P_lds[head][key]
#pragma unroll
  for (int ti = 0; ti < 8; ++ti) {
    int mt = w + 4 * ti;
    if (mt >= nt16) break;
    uint lo = (uint)f2bf(sreg[ti][0]) | ((uint)f2bf(sreg[ti][1]) << 16);
    uint hi = (uint)f2bf(sreg[ti][2]) | ((uint)f2bf(sreg[ti][3]) << 16);
    uint* dst = (uint*)&P_lds[h][16 * mt + 4 * g];
    dst[0] = lo;
    dst[1] = hi;
  }

  // ---- PV: wave w owns dim-groups w*8 .. w*8+7 ----
  f4v oacc[8];
#pragma unroll
  for (int j = 0; j < 8; ++j) oacc[j] = (f4v){0.f, 0.f, 0.f, 0.f};

  const uint vt_base = (uint)(size_t)(&VT[0]);

  for (int kc = 0; kc < nkc; ++kc) {
    __syncthreads();  // P ready (1st iter) / prev chunk's tr_reads done
    // stage 32 keys x 512 dims, subtiled [dg][key][16]
#pragma unroll
    for (int ii = 0; ii < 8; ++ii) {
      int i = tid + ii * 256;  // 0..2047
      int key = i >> 6, c = i & 63;
      const ushort* src = kvbf + (size_t)list[kc * 32 + key] * QKD + c * 8;
      short8 v = *(const short8*)src;
      *(short8*)&VT[(((c >> 1) * 32) + key) * 16 + (c & 1) * 8] = v;
    }
    __syncthreads();

    short8 pa = *(const short8*)&P_lds[h][kc * 32 + g * 8];
    u32x2 b0[8], b1[8];
#pragma unroll
    for (int j = 0; j < 8; ++j) {
      // m156 pattern: lane at byte 8*(lane&15) within the group's 128B window
      uint addr = vt_base + (uint)((w * 8 + j) * 1024 + g * 256 + h * 8);
      asm volatile("ds_read_b64_tr_b16 %0, %1 offset:0" : "=v"(b0[j]) : "v"(addr));
      asm volatile("ds_read_b64_tr_b16 %0, %1 offset:128" : "=v"(b1[j]) : "v"(addr));
    }
    asm volatile("s_waitcnt lgkmcnt(0)" ::: "memory");
    __builtin_amdgcn_sched_barrier(0);
#pragma unroll
    for (int j = 0; j < 8; ++j) {
      union { u32x4 u; short8 sv; } bb;
      bb.u = (u32x4){b0[j][0], b0[j][1], b1[j][0], b1[j][1]};
      oacc[j] = __builtin_amdgcn_mfma_f32_16x16x32_bf16(pa, bb.sv, oacc[j], 0, 0, 0);
    }
  }

  // ---- epilogue: D row = head 4g+r, col = dim (w*8+j)*16 + h ----
  float rd[4];
#pragma unroll
  for (int r = 0; r < 4; ++r) rd[r] = denom_lds[4 * g + r];
  ushort* orow = attn_out + (size_t)s * HKV;
#pragma unroll
  for (int j = 0; j < 8; ++j) {
    int dcol = (w * 8 + j) * 16 + h;
#pragma unroll
    for (int r = 0; r < 4; ++r)
      orow[(size_t)(4 * g + r) * KVLORA + dcol] = f2bf(oacc[j][r] * rd[r]);
  }
}

// ---------------------------------------------------------------------------
extern "C" void kernel_launch(void* const* d_in, const int* in_sizes, int n_in,
                              void* d_out, int out_size, void* d_ws, size_t ws_size,
                              hipStream_t stream) {
  const float* hidden   = (const float*)d_in[0];
  const float* cosp     = (const float*)d_in[1];
  const float* sinp     = (const float*)d_in[2];
  const int*   topk     = (const int*)d_in[3];
  const float* w_q_a    = (const float*)d_in[4];
  const float* w_q_a_ln = (const float*)d_in[5];
  const float* w_q_b    = (const float*)d_in[6];
  const float* w_kv_a   = (const float*)d_in[7];
  const float* w_kv_ln  = (const float*)d_in[8];
  const float* w_o      = (const float*)d_in[9];
  float* out = (float*)d_out;

  char* base = (char*)d_ws;
  // region0 (32MB): hid_bf | wqa_bf | qa | qa_bf -> later aliased as attn_bf
  ushort* hid_bf  = (ushort*)(base + 0);             //  8,388,608
  ushort* wqa_bf  = (ushort*)(base + 8388608);       //  6,291,456
  float*  qa      = (float*) (base + 14680064);      // 12,582,912
  ushort* qa_bf   = (ushort*)(base + 27262976);      //  6,291,456
  ushort* attn_bf = (ushort*)(base + 0);             // 33,554,432 (alias)
  ushort* wqb_bf  = (ushort*)(base + 33554432);      // 28,311,552
  ushort* wkv_bf  = (ushort*)(base + 61865984);      //  2,621,440
  ushort* wo_bf   = (ushort*)(base + 64487424);      // 33,554,432
  ushort* qbuf_bf = (ushort*)(base + 98041856);      // 37,748,736 (S x 16 x 576)
  float*  ckv     = (float*) (base + 135790592);     //  5,242,880
  ushort* kv_bf   = (ushort*)(base + 141033472);     //  2,359,296

  // casts
  cast_bf16<<<(S_LEN * DMODEL / 8 + 255) / 256, 256, 0, stream>>>(hidden, hid_bf, S_LEN * DMODEL / 8);
  cast_bf16<<<(QLORA * DMODEL / 8 + 255) / 256, 256, 0, stream>>>(w_q_a, wqa_bf, QLORA * DMODEL / 8);
  cast_bf16<<<(HQK * QLORA / 8 + 255) / 256, 256, 0, stream>>>(w_q_b, wqb_bf, HQK * QLORA / 8);
  cast_pad_bf16<<<(NKV_PAD * DMODEL / 8 + 255) / 256, 256, 0, stream>>>(w_kv_a, wkv_bf, QKD, DMODEL, NKV_PAD * DMODEL / 8);
  cast_bf16<<<(DMODEL * HKV / 8 + 255) / 256, 256, 0, stream>>>(w_o, wo_bf, DMODEL * HKV / 8);

  // q_a = hidden @ w_q_a^T ; rmsnorm -> bf16
  gemm_bf16_nt<<<dim3(QLORA / 128, S_LEN / 128), 256, 0, stream>>>(
      hid_bf, wqa_bf, qa, S_LEN, QLORA, DMODEL);
  rmsnorm_bf16<<<S_LEN, 256, 0, stream>>>(qa, w_q_a_ln, qa_bf, QLORA, 1.f / QLORA);

  // q = q_resid @ w_q_b^T (bf16 out) ; rope + scale in place
  gemm_bf16_nt_bf16out<<<dim3(HQK / 128, S_LEN / 128), 256, 0, stream>>>(
      qa_bf, wqb_bf, qbuf_bf, S_LEN, HQK, QLORA);
  rope_scale<<<S_LEN, 256, 0, stream>>>(qbuf_bf, cosp, sinp);

  // ckv = hidden @ w_kv_a^T (padded N) ; kv build -> bf16
  gemm_bf16_nt<<<dim3(NKV_PAD / 128, S_LEN / 128), 256, 0, stream>>>(
      hid_bf, wkv_bf, ckv, S_LEN, NKV_PAD, DMODEL);
  kv_build_bf<<<S_LEN, 64, 0, stream>>>(ckv, w_kv_ln, cosp, sinp, kv_bf);

  // MFMA sparse attention
  attn_mfma<<<S_LEN, 256, 0, stream>>>(qbuf_bf, kv_bf, topk, attn_bf);

  // out = attn @ w_o^T
  gemm_bf16_nt<<<dim3(DMODEL / 128, S_LEN / 128), 256, 0, stream>>>(
      attn_bf, wo_bf, out, S_LEN, DMODEL, HKV);
}

// Round 6
// 635.074 us; speedup vs baseline: 4.2755x; 1.1902x over previous
//
#include <hip/hip_runtime.h>
#include <hip/hip_bf16.h>
#include <cstdint>

#define S_LEN   2048
#define DMODEL  2048
#define HHEADS  16
#define KVLORA  512
#define ROPE_D  64
#define QKD     576     // KVLORA + ROPE_D
#define QLORA   1536
#define TOPK    512
#define HQK     (HHEADS * QKD)     // 9216
#define HKV     (HHEADS * KVLORA)  // 8192
#define NKV_PAD 640     // 576 padded to a multiple of 128

typedef __attribute__((ext_vector_type(4))) float f4v;
typedef __attribute__((ext_vector_type(8))) short short8;
typedef __attribute__((ext_vector_type(2))) unsigned int u32x2;
typedef __attribute__((ext_vector_type(4))) unsigned int u32x4;

__device__ __forceinline__ ushort f2bf(float f) {
  uint32_t u = __float_as_uint(f);
  uint32_t r = (u + 0x7fffu + ((u >> 16) & 1u)) >> 16;
  return (ushort)r;
}
__device__ __forceinline__ float bf2f(ushort u) {
  return __uint_as_float(((uint32_t)u) << 16);
}

__device__ __forceinline__ void gload_lds16(const ushort* g, ushort* l) {
  __builtin_amdgcn_global_load_lds(
      (const __attribute__((address_space(1))) unsigned int*)(uintptr_t)g,
      (__attribute__((address_space(3))) unsigned int*)(uintptr_t)l,
      16, 0, 0);
}

// ---------------------------------------------------------------------------
// bf16 NT GEMM, templated tile, double-buffered 2-phase pipeline:
//   STAGE(next) issued BEFORE ds_read+MFMA of current -> staging flight hides
//   under compute; one __syncthreads per K-step (drains vmcnt+lgkmcnt).
// C[M,N] = A[M,K] * B[N,K]^T. 4 waves. Wave grid WGM x WGN, frag-rep MR x NR.
// ---------------------------------------------------------------------------
template<int BM, int BN, int WGM, int WGN, bool BF16OUT>
__global__ __launch_bounds__(256)
void gemm_nt_t(const ushort* __restrict__ A, const ushort* __restrict__ B,
               void* __restrict__ Cv, int M, int N, int K) {
  constexpr int MR = BM / (WGM * 16);
  constexpr int NR = BN / (WGN * 16);
  __shared__ ushort As[2][BM * 32];
  __shared__ ushort Bs[2][BN * 32];
  const int tid = threadIdx.x;
  const int lane = tid & 63;
  const int w = tid >> 6;
  const int wr = w / WGN, wc = w % WGN;
  const int bm = blockIdx.y * BM, bn = blockIdx.x * BN;
  const int srow16 = w * 16 + (lane >> 2);   // row within a 64-row staging slab
  const int scol = (lane & 3) * 8;           // ushort col within row (16B chunk)
  const int koff = (lane >> 4) * 8;
  const int fr = lane & 15;

  f4v acc[MR][NR];
#pragma unroll
  for (int m = 0; m < MR; ++m)
#pragma unroll
    for (int n = 0; n < NR; ++n) acc[m][n] = (f4v){0.f, 0.f, 0.f, 0.f};

  auto STAGE = [&](int buf, int k0) {
#pragma unroll
    for (int r0 = 0; r0 < BM; r0 += 64)
      gload_lds16(A + (size_t)(bm + r0 + srow16) * K + k0 + scol,
                  &As[buf][(r0 + w * 16) * 32]);
#pragma unroll
    for (int r0 = 0; r0 < BN; r0 += 64)
      gload_lds16(B + (size_t)(bn + r0 + srow16) * K + k0 + scol,
                  &Bs[buf][(r0 + w * 16) * 32]);
  };

  const int nt = K / 32;
  int cur = 0;
  STAGE(0, 0);
  for (int t = 0; t < nt; ++t) {
    __syncthreads();  // drains vmcnt (buf[cur] staged) + prev ds_reads
    if (t + 1 < nt) STAGE(cur ^ 1, (t + 1) * 32);
    short8 a[MR], b[NR];
#pragma unroll
    for (int m = 0; m < MR; ++m)
      a[m] = *(const short8*)&As[cur][(wr * MR * 16 + m * 16 + fr) * 32 + koff];
#pragma unroll
    for (int n = 0; n < NR; ++n)
      b[n] = *(const short8*)&Bs[cur][(wc * NR * 16 + n * 16 + fr) * 32 + koff];
#pragma unroll
    for (int m = 0; m < MR; ++m)
#pragma unroll
      for (int n = 0; n < NR; ++n)
        acc[m][n] = __builtin_amdgcn_mfma_f32_16x16x32_bf16(a[m], b[n], acc[m][n], 0, 0, 0);
    cur ^= 1;
  }

  // C/D layout (m89-verified): col = lane&15, row = (lane>>4)*4 + reg
  const int crow0 = bm + wr * MR * 16 + (lane >> 4) * 4;
  const int ccol0 = bn + wc * NR * 16 + fr;
  if constexpr (BF16OUT) {
    ushort* C = (ushort*)Cv;
#pragma unroll
    for (int m = 0; m < MR; ++m)
#pragma unroll
      for (int n = 0; n < NR; ++n)
#pragma unroll
        for (int r = 0; r < 4; ++r)
          C[(size_t)(crow0 + m * 16 + r) * N + ccol0 + n * 16] = f2bf(acc[m][n][r]);
  } else {
    float* C = (float*)Cv;
#pragma unroll
    for (int m = 0; m < MR; ++m)
#pragma unroll
      for (int n = 0; n < NR; ++n)
#pragma unroll
        for (int r = 0; r < 4; ++r)
          C[(size_t)(crow0 + m * 16 + r) * N + ccol0 + n * 16] = acc[m][n][r];
  }
}

// ---------------------------------------------------------------------------
// fp32 -> bf16 casts
// ---------------------------------------------------------------------------
__global__ __launch_bounds__(256)
void cast_bf16(const float* __restrict__ in, ushort* __restrict__ out, int n8) {
  int i = blockIdx.x * 256 + threadIdx.x;
  if (i >= n8) return;
  float4 v0 = ((const float4*)in)[i * 2];
  float4 v1 = ((const float4*)in)[i * 2 + 1];
  short8 r;
  r[0] = f2bf(v0.x); r[1] = f2bf(v0.y); r[2] = f2bf(v0.z); r[3] = f2bf(v0.w);
  r[4] = f2bf(v1.x); r[5] = f2bf(v1.y); r[6] = f2bf(v1.z); r[7] = f2bf(v1.w);
  ((short8*)out)[i] = r;
}

__global__ __launch_bounds__(256)
void cast_pad_bf16(const float* __restrict__ in, ushort* __restrict__ out,
                   int rows_in, int cols, int n8) {
  int i = blockIdx.x * 256 + threadIdx.x;
  if (i >= n8) return;
  int row = (i * 8) / cols;
  short8 r = (short8){0, 0, 0, 0, 0, 0, 0, 0};
  if (row < rows_in) {
    float4 v0 = ((const float4*)in)[i * 2];
    float4 v1 = ((const float4*)in)[i * 2 + 1];
    r[0] = f2bf(v0.x); r[1] = f2bf(v0.y); r[2] = f2bf(v0.z); r[3] = f2bf(v0.w);
    r[4] = f2bf(v1.x); r[5] = f2bf(v1.y); r[6] = f2bf(v1.z); r[7] = f2bf(v1.w);
  }
  ((short8*)out)[i] = r;
}

// ---------------------------------------------------------------------------
// RMSNorm fp32 -> bf16
// ---------------------------------------------------------------------------
__global__ __launch_bounds__(256)
void rmsnorm_bf16(const float* __restrict__ x, const float* __restrict__ w,
                  ushort* __restrict__ y, int n, float inv_n) {
  const int row = blockIdx.x;
  const float* p = x + (size_t)row * n;
  ushort* yp = y + (size_t)row * n;
  const int tid = threadIdx.x;
  const int n4 = n / 4;
  float ss = 0.f;
  for (int i = tid; i < n4; i += 256) {
    float4 v = ((const float4*)p)[i];
    ss += v.x * v.x + v.y * v.y + v.z * v.z + v.w * v.w;
  }
#pragma unroll
  for (int d = 32; d >= 1; d >>= 1) ss += __shfl_xor(ss, d);
  __shared__ float wsum[4];
  if ((tid & 63) == 0) wsum[tid >> 6] = ss;
  __syncthreads();
  float tot = wsum[0] + wsum[1] + wsum[2] + wsum[3];
  float inv = rsqrtf(tot * inv_n + 1e-6f);
  for (int i = tid; i < n4; i += 256) {
    float4 v = ((const float4*)p)[i];
    float4 g = ((const float4*)w)[i];
    ushort4 o;
    o.x = f2bf(g.x * v.x * inv); o.y = f2bf(g.y * v.y * inv);
    o.z = f2bf(g.z * v.z * inv); o.w = f2bf(g.w * v.w * inv);
    ((ushort4*)yp)[i] = o;
  }
}

// ---------------------------------------------------------------------------
// RoPE + scale (576^-0.5) in place on bf16 q [S][16][576]
// ---------------------------------------------------------------------------
__global__ __launch_bounds__(256)
void rope_scale(ushort* __restrict__ q, const float* __restrict__ cs,
                const float* __restrict__ sn) {
  const int s = blockIdx.x;
  const int tid = threadIdx.x;
  __shared__ float c_s[64], s_s[64];
  if (tid < 64) { c_s[tid] = cs[s * 64 + tid]; s_s[tid] = sn[s * 64 + tid]; }
  __syncthreads();
  const float SC = 0.041666666666666664f;  // 576^-0.5
  ushort* qrow = q + (size_t)s * HQK;
  for (int i = tid; i < 1024; i += 256) {
    int hh = i >> 6, c = i & 63;
    ushort* p = qrow + hh * QKD + c * 8;
    short8 v = *(short8*)p;
#pragma unroll
    for (int e = 0; e < 8; ++e) v[e] = (short)f2bf(bf2f((ushort)v[e]) * SC);
    *(short8*)p = v;
  }
  for (int i = tid; i < HHEADS * 32; i += 256) {
    int hh = i >> 5, r = i & 31;
    ushort* bp = qrow + hh * QKD + KVLORA;
    float x1 = bf2f(bp[r]), x2 = bf2f(bp[r + 32]);
    bp[r]      = f2bf((x1 * c_s[r] - x2 * s_s[r]) * SC);
    bp[r + 32] = f2bf((x2 * c_s[r + 32] + x1 * s_s[r + 32]) * SC);
  }
}

// ---------------------------------------------------------------------------
// kv row build -> bf16: rmsnorm(ckv[:512])*w_ln || rope(ckv[512:576])
// ---------------------------------------------------------------------------
__global__ __launch_bounds__(64)
void kv_build_bf(const float* __restrict__ ckv, const float* __restrict__ lnw,
                 const float* __restrict__ cs, const float* __restrict__ sn,
                 ushort* __restrict__ kvbf) {
  const int s = blockIdx.x;
  const int lane = threadIdx.x;
  const float* row = ckv + (size_t)s * NKV_PAD;
  float4 a = ((const float4*)row)[lane * 2];
  float4 b = ((const float4*)row)[lane * 2 + 1];
  float ss = a.x * a.x + a.y * a.y + a.z * a.z + a.w * a.w +
             b.x * b.x + b.y * b.y + b.z * b.z + b.w * b.w;
#pragma unroll
  for (int d = 32; d >= 1; d >>= 1) ss += __shfl_xor(ss, d);
  float inv = rsqrtf(ss * (1.f / KVLORA) + 1e-6f);
  float4 wa = ((const float4*)lnw)[lane * 2];
  float4 wb = ((const float4*)lnw)[lane * 2 + 1];
  ushort* orow = kvbf + (size_t)s * QKD;
  short8 o;
  o[0] = f2bf(a.x * wa.x * inv); o[1] = f2bf(a.y * wa.y * inv);
  o[2] = f2bf(a.z * wa.z * inv); o[3] = f2bf(a.w * wa.w * inv);
  o[4] = f2bf(b.x * wb.x * inv); o[5] = f2bf(b.y * wb.y * inv);
  o[6] = f2bf(b.z * wb.z * inv); o[7] = f2bf(b.w * wb.w * inv);
  *(short8*)(orow + lane * 8) = o;
  float x = row[KVLORA + lane];
  int partner = (lane < 32) ? lane + 32 : lane - 32;
  float other = row[KVLORA + partner];
  float rot = (lane < 32) ? -other : other;
  orow[KVLORA + lane] = f2bf(x * cs[s * 64 + lane] + rot * sn[s * 64 + lane]);
}

// ---------------------------------------------------------------------------
// MFMA sparse attention. One block per query row. (unchanged from round 5)
// ---------------------------------------------------------------------------
__global__ __launch_bounds__(256)
void attn_mfma(const ushort* __restrict__ qbf, const ushort* __restrict__ kvbf,
               const int* __restrict__ topk, ushort* __restrict__ attn_out) {
  const int s = blockIdx.x;
  const int tid = threadIdx.x;
  const int lane = tid & 63;
  const int w = tid >> 6;
  const int g = lane >> 4;   // 0..3
  const int h = lane & 15;   // fragment row (key for A / head for B/D-col)

  __shared__ unsigned int msk[64];
  __shared__ int list[544];
  __shared__ int nk_s;
  __shared__ float wred[4][16];
  __shared__ float denom_lds[16];
  __shared__ ushort P_lds[16][520];     // [head][key] bf16, unnormalized probs
  __shared__ ushort VT[32 * 32 * 16];   // [dimgroup][key][16] per 32-key chunk

  if (tid < 64) msk[tid] = 0u;
  {  // zero P_lds (pad keys must contribute 0 to PV)
    uint* pz = (uint*)&P_lds[0][0];
    for (int i = tid; i < 16 * 260; i += 256) pz[i] = 0u;
  }
  __syncthreads();
  for (int i = tid; i < TOPK; i += 256) {
    int t = topk[(size_t)s * TOPK + i];
    if (t <= s) atomicOr(&msk[t >> 5], 1u << (t & 31));
  }
  __syncthreads();

  if (w == 0) {
    unsigned int b = msk[lane];
    int cnt = __popc(b);
    int incl = cnt;
#pragma unroll
    for (int d = 1; d < 64; d <<= 1) {
      int o = __shfl_up(incl, d);
      if (lane >= d) incl += o;
    }
    if (lane == 63) nk_s = incl;
    int pos = incl - cnt;
    while (b) {
      int bit = __ffs(b) - 1;
      list[pos++] = (lane << 5) + bit;
      b &= b - 1;
    }
    int nkv = __shfl(incl, 63);
    for (int i = nkv + lane; i < 544; i += 64) list[i] = s;  // pad with own row
  }

  // q B-frags: head h, all 18 k-steps (q pre-scaled by 576^-0.5)
  short8 qf[18];
  const ushort* qrow = qbf + (size_t)s * HQK + h * QKD;
#pragma unroll
  for (int kk = 0; kk < 18; ++kk)
    qf[kk] = *(const short8*)(qrow + kk * 32 + g * 8);

  __syncthreads();
  const int nk = nk_s;
  const int nt16 = (nk + 15) >> 4;
  const int nkc = (nk + 31) >> 5;

  // ---- scores: wave w owns m-tiles {w, w+4, w+8, ...}; pairs for ILP ----
  float sreg[8][4];
#pragma unroll
  for (int t2 = 0; t2 < 4; ++t2) {
    const int mtA = w + 8 * t2;
    const int mtB = mtA + 4;
    if (mtA >= nt16) break;
    const bool hasB = (mtB < nt16);
    const ushort* rA = kvbf + (size_t)list[mtA * 16 + h] * QKD;
    const ushort* rB = kvbf + (size_t)list[(hasB ? mtB : mtA) * 16 + h] * QKD;
    f4v aA = (f4v){0.f, 0.f, 0.f, 0.f};
    f4v aB = (f4v){0.f, 0.f, 0.f, 0.f};
#pragma unroll 6
    for (int kk = 0; kk < 18; ++kk) {
      short8 kfA = *(const short8*)(rA + kk * 32 + g * 8);
      short8 kfB = *(const short8*)(rB + kk * 32 + g * 8);
      aA = __builtin_amdgcn_mfma_f32_16x16x32_bf16(kfA, qf[kk], aA, 0, 0, 0);
      aB = __builtin_amdgcn_mfma_f32_16x16x32_bf16(kfB, qf[kk], aB, 0, 0, 0);
    }
#pragma unroll
    for (int r = 0; r < 4; ++r) {
      sreg[2 * t2][r] = aA[r];
      sreg[2 * t2 + 1][r] = aB[r];
    }
  }

  // ---- softmax (lane holds keys 16*(w+4*ti)+4g+r for head h) ----
  float mloc = -3e38f;
#pragma unroll
  for (int ti = 0; ti < 8; ++ti) {
    int keyb = 16 * (w + 4 * ti) + 4 * g;
#pragma unroll
    for (int r = 0; r < 4; ++r) {
      if (keyb + r >= nk) sreg[ti][r] = -3e38f;
      mloc = fmaxf(mloc, sreg[ti][r]);
    }
  }
  mloc = fmaxf(mloc, __shfl_xor(mloc, 16));
  mloc = fmaxf(mloc, __shfl_xor(mloc, 32));
  if (g == 0) wred[w][h] = mloc;
  __syncthreads();
  float mg = fmaxf(fmaxf(wred[0][h], wred[1][h]), fmaxf(wred[2][h], wred[3][h]));
  float psum = 0.f;
#pragma unroll
  for (int ti = 0; ti < 8; ++ti)
#pragma unroll
    for (int r = 0; r < 4; ++r) {
      float p = __expf(sreg[ti][r] - mg);
      sreg[ti][r] = p;
      psum += p;
    }
  psum += __shfl_xor(psum, 16);
  psum += __shfl_xor(psum, 32);
  __syncthreads();  // everyone done reading wred (max) before overwrite
  if (g == 0) wred[w][h] = psum;
  __syncthreads();
  float tot = wred[0][h] + wred[1][h] + wred[2][h] + wred[3][h];
  if (w == 0 && g == 0) denom_lds[h] = 1.0f / tot;

  // write P (bf16, unnormalized) to P_lds[head][key]
#pragma unroll
  for (int ti = 0; ti < 8; ++ti) {
    int mt = w + 4 * ti;
    if (mt >= nt16) break;
    uint lo = (uint)f2bf(sreg[ti][0]) | ((uint)f2bf(sreg[ti][1]) << 16);
    uint hi = (uint)f2bf(sreg[ti][2]) | ((uint)f2bf(sreg[ti][3]) << 16);
    uint* dst = (uint*)&P_lds[h][16 * mt + 4 * g];
    dst[0] = lo;
    dst[1] = hi;
  }

  // ---- PV: wave w owns dim-groups w*8 .. w*8+7 ----
  f4v oacc[8];
#pragma unroll
  for (int j = 0; j < 8; ++j) oacc[j] = (f4v){0.f, 0.f, 0.f, 0.f};

  const uint vt_base = (uint)(size_t)(&VT[0]);

  for (int kc = 0; kc < nkc; ++kc) {
    __syncthreads();  // P ready (1st iter) / prev chunk's tr_reads done
    // stage 32 keys x 512 dims, subtiled [dg][key][16]
#pragma unroll
    for (int ii = 0; ii < 8; ++ii) {
      int i = tid + ii * 256;  // 0..2047
      int key = i >> 6, c = i & 63;
      const ushort* src = kvbf + (size_t)list[kc * 32 + key] * QKD + c * 8;
      short8 v = *(const short8*)src;
      *(short8*)&VT[(((c >> 1) * 32) + key) * 16 + (c & 1) * 8] = v;
    }
    __syncthreads();

    short8 pa = *(const short8*)&P_lds[h][kc * 32 + g * 8];
    u32x2 b0[8], b1[8];
#pragma unroll
    for (int j = 0; j < 8; ++j) {
      // m156 pattern: lane at byte 8*(lane&15) within the group's 128B window
      uint addr = vt_base + (uint)((w * 8 + j) * 1024 + g * 256 + h * 8);
      asm volatile("ds_read_b64_tr_b16 %0, %1 offset:0" : "=v"(b0[j]) : "v"(addr));
      asm volatile("ds_read_b64_tr_b16 %0, %1 offset:128" : "=v"(b1[j]) : "v"(addr));
    }
    asm volatile("s_waitcnt lgkmcnt(0)" ::: "memory");
    __builtin_amdgcn_sched_barrier(0);
#pragma unroll
    for (int j = 0; j < 8; ++j) {
      union { u32x4 u; short8 sv; } bb;
      bb.u = (u32x4){b0[j][0], b0[j][1], b1[j][0], b1[j][1]};
      oacc[j] = __builtin_amdgcn_mfma_f32_16x16x32_bf16(pa, bb.sv, oacc[j], 0, 0, 0);
    }
  }

  // ---- epilogue: D row = head 4g+r, col = dim (w*8+j)*16 + h ----
  float rd[4];
#pragma unroll
  for (int r = 0; r < 4; ++r) rd[r] = denom_lds[4 * g + r];
  ushort* orow = attn_out + (size_t)s * HKV;
#pragma unroll
  for (int j = 0; j < 8; ++j) {
    int dcol = (w * 8 + j) * 16 + h;
#pragma unroll
    for (int r = 0; r < 4; ++r)
      orow[(size_t)(4 * g + r) * KVLORA + dcol] = f2bf(oacc[j][r] * rd[r]);
  }
}

// ---------------------------------------------------------------------------
extern "C" void kernel_launch(void* const* d_in, const int* in_sizes, int n_in,
                              void* d_out, int out_size, void* d_ws, size_t ws_size,
                              hipStream_t stream) {
  const float* hidden   = (const float*)d_in[0];
  const float* cosp     = (const float*)d_in[1];
  const float* sinp     = (const float*)d_in[2];
  const int*   topk     = (const int*)d_in[3];
  const float* w_q_a    = (const float*)d_in[4];
  const float* w_q_a_ln = (const float*)d_in[5];
  const float* w_q_b    = (const float*)d_in[6];
  const float* w_kv_a   = (const float*)d_in[7];
  const float* w_kv_ln  = (const float*)d_in[8];
  const float* w_o      = (const float*)d_in[9];
  float* out = (float*)d_out;

  char* base = (char*)d_ws;
  // region0 (32MB): hid_bf | wqa_bf | qa | qa_bf -> later aliased as attn_bf
  ushort* hid_bf  = (ushort*)(base + 0);             //  8,388,608
  ushort* wqa_bf  = (ushort*)(base + 8388608);       //  6,291,456
  float*  qa      = (float*) (base + 14680064);      // 12,582,912
  ushort* qa_bf   = (ushort*)(base + 27262976);      //  6,291,456
  ushort* attn_bf = (ushort*)(base + 0);             // 33,554,432 (alias)
  ushort* wqb_bf  = (ushort*)(base + 33554432);      // 28,311,552
  ushort* wkv_bf  = (ushort*)(base + 61865984);      //  2,621,440
  ushort* wo_bf   = (ushort*)(base + 64487424);      // 33,554,432
  ushort* qbuf_bf = (ushort*)(base + 98041856);      // 37,748,736 (S x 16 x 576)
  float*  ckv     = (float*) (base + 135790592);     //  5,242,880
  ushort* kv_bf   = (ushort*)(base + 141033472);     //  2,359,296

  // casts
  cast_bf16<<<(S_LEN * DMODEL / 8 + 255) / 256, 256, 0, stream>>>(hidden, hid_bf, S_LEN * DMODEL / 8);
  cast_bf16<<<(QLORA * DMODEL / 8 + 255) / 256, 256, 0, stream>>>(w_q_a, wqa_bf, QLORA * DMODEL / 8);
  cast_bf16<<<(HQK * QLORA / 8 + 255) / 256, 256, 0, stream>>>(w_q_b, wqb_bf, HQK * QLORA / 8);
  cast_pad_bf16<<<(NKV_PAD * DMODEL / 8 + 255) / 256, 256, 0, stream>>>(w_kv_a, wkv_bf, QKD, DMODEL, NKV_PAD * DMODEL / 8);
  cast_bf16<<<(DMODEL * HKV / 8 + 255) / 256, 256, 0, stream>>>(w_o, wo_bf, DMODEL * HKV / 8);

  // q_a = hidden @ w_q_a^T ; rmsnorm -> bf16   (64x128 tile, 384 blocks)
  gemm_nt_t<64, 128, 1, 4, false><<<dim3(QLORA / 128, S_LEN / 64), 256, 0, stream>>>(
      hid_bf, wqa_bf, qa, S_LEN, QLORA, DMODEL);
  rmsnorm_bf16<<<S_LEN, 256, 0, stream>>>(qa, w_q_a_ln, qa_bf, QLORA, 1.f / QLORA);

  // q = q_resid @ w_q_b^T (bf16 out) ; rope + scale   (128x128, 1152 blocks)
  gemm_nt_t<128, 128, 2, 2, true><<<dim3(HQK / 128, S_LEN / 128), 256, 0, stream>>>(
      qa_bf, wqb_bf, qbuf_bf, S_LEN, HQK, QLORA);
  rope_scale<<<S_LEN, 256, 0, stream>>>(qbuf_bf, cosp, sinp);

  // ckv = hidden @ w_kv_a^T (padded N)   (64x64 tile, 320 blocks)
  gemm_nt_t<64, 64, 2, 2, false><<<dim3(NKV_PAD / 64, S_LEN / 64), 256, 0, stream>>>(
      hid_bf, wkv_bf, ckv, S_LEN, NKV_PAD, DMODEL);
  kv_build_bf<<<S_LEN, 64, 0, stream>>>(ckv, w_kv_ln, cosp, sinp, kv_bf);

  // MFMA sparse attention
  attn_mfma<<<S_LEN, 256, 0, stream>>>(qbuf_bf, kv_bf, topk, attn_bf);

  // out = attn @ w_o^T   (64x128 tile, 512 blocks)
  gemm_nt_t<64, 128, 1, 4, false><<<dim3(DMODEL / 128, S_LEN / 64), 256, 0, stream>>>(
      attn_bf, wo_bf, out, S_LEN, DMODEL, HKV);
}